// Round 7
// baseline (182.614 us; speedup 1.0000x reference)
//
#include <hip/hip_runtime.h>
#include <math.h>

// VIN forward on MI355X — single fused kernel, 128 WGs x 512 thr, 8 px/thread.
// Sizes: N=128, H=W=64, CH_I=2, CH_H=150, CH_Q=10, N_ACT=8, VInum=36.
//
// R17 -> R18 (K-loop operand residency):
//  R17 counters: VGPR=64, SGPR=112 -> the 45 v2f w_sw weights are in NEITHER
//  register file (90 SGPRs don't fit beside bases in ~102; VGPR alloc is 64)
//  => ~45 s_loads re-issued EVERY iteration. SMEM returns out-of-order, so
//  mixed SMEM+DS in flight forces lgkmcnt(0) full drains per chunk — the
//  serialization that kept iterations at ~2.4us vs the 0.7us VALU floor
//  (and why R17's sprinkling barely helped). Fix: back to 512 thr (LDS
//  already limits to 1 WG/CU -> 2 waves/SIMD; VGPR budget 256) with
//  wreg[45] VGPR-resident; keep R16's pad-68 16B-aligned b128 loads (3 per
//  stencil row cover both 4-px halves), R14's vprev center row, R17's
//  row-chunk schedule (half A compute covers half B loads). K-loop is pure
//  VALU + in-order DS. Per-px FP order unchanged -> bit-identical output.

typedef float v2f __attribute__((ext_vector_type(2)));

static __device__ __forceinline__ v2f splat2(float s) { v2f r; r.x = s; r.y = s; return r; }
static __device__ __forceinline__ v2f pkfma(v2f w, float v, v2f a) {
#if __has_builtin(__builtin_elementwise_fma)
    return __builtin_elementwise_fma(w, splat2(v), a);
#else
    v2f r; r.x = fmaf(w.x, v, a.x); r.y = fmaf(w.y, v, a.y); return r;
#endif
}
static __device__ __forceinline__ v2f pkmax(v2f a, v2f b) {
#if __has_builtin(__builtin_elementwise_max)
    return __builtin_elementwise_max(a, b);
#else
    v2f r; r.x = fmaxf(a.x, b.x); r.y = fmaxf(a.y, b.y); return r;
#endif
}

#define XROW 69
#define RROW 68                  // rs row stride; idx = (grow+1)*68 + col + 2
#define VROW2 68                 // vpool row stride; idx = (grow+1)*68 + col + 2
#define VSTR2 (66 * VROW2)       // 4488 floats per v buffer

__global__ void
__attribute__((amdgpu_flat_work_group_size(512, 512)))
__attribute__((amdgpu_waves_per_eu(2, 2)))
vin_kernel(const float* __restrict__ x,
           const int* __restrict__ S1,
           const int* __restrict__ S2,
           const int* __restrict__ VInum,
           const float* __restrict__ w0,
           const float* __restrict__ b0,
           const float* __restrict__ w_r,
           const float* __restrict__ w_q,
           const float* __restrict__ w_sw,
           const float* __restrict__ w_sw2,
           const float* __restrict__ w_dense,
           float* __restrict__ out) {
    const int b = blockIdx.x;
    const int t = threadIdx.x;

    __shared__ float xs0[68 * XROW];     // x ch0, [y+2][x+2], 2-halo of zeros
    __shared__ float xs1[68 * XROW];     // x ch1
    __shared__ float rs[66 * RROW];      // r, pad-2 layout, zero halos
    __shared__ float vpool[2 * VSTR2];   // v double buffer, pad-2 layout
    __shared__ float wtA[1620];          // P chunk partials: 162 entries x 10
    __shared__ float Pp[450];            // P[d][e5x5][ci], zero-init
    __shared__ float Bt[90];             // bias chunk partials
    __shared__ float Bv[9];              // B[d] = w_r[d].b0
    __shared__ float W5c[459];           // 9 classes x (50 weights + bias)
    __shared__ v2f   swv2[45];           // w_sw v-part action-pairs: [d][ap]
    __shared__ float qsel[10];

    // ---- zero LDS (halos must be 0; Pp must be 0 for invalid combos) ----
    for (int i = t; i < 68 * XROW; i += 512) { xs0[i] = 0.f; xs1[i] = 0.f; }
    for (int i = t; i < 66 * RROW; i += 512) rs[i] = 0.f;
    for (int i = t; i < 2 * VSTR2; i += 512) vpool[i] = 0.f;
    if (t < 450) Pp[t] = 0.f;
    if (t < 45) {
        int d = t / 5, ap = t - d * 5;
        v2f w; w.x = w_sw[d * 20 + 10 + 2 * ap]; w.y = w_sw[d * 20 + 10 + 2 * ap + 1];
        swv2[t] = w;
    }
    __syncthreads();

    const int row = t >> 3;          // 0..63
    const int cb  = (t & 7) << 3;    // 0,8,...,56  (8 px per thread)

    // ---- stage x into split planes (16 contiguous floats = 4x float4) ----
    {
        const float* xb = x + (size_t)b * 64 * 64 * 2;
        const float4* xp = (const float4*)(xb + (row * 64 + cb) * 2);
        #pragma unroll
        for (int g = 0; g < 4; ++g) {
            float4 v4 = xp[g];
            int px = cb + g * 2;
            xs0[(row + 2) * XROW + px + 2] = v4.x;
            xs1[(row + 2) * XROW + px + 2] = v4.y;
            xs0[(row + 2) * XROW + px + 3] = v4.z;
            xs1[(row + 2) * XROW + px + 3] = v4.w;
        }
    }
    // ---- round A: P chunk partials (1620 items) + bias chunks (90) ----
    for (int idx = t; idx < 1620; idx += 512) {
        int entry = idx / 10, ch = idx - entry * 10;
        int d = entry / 18, rem = entry % 18;
        int uu = rem >> 1, ci = rem & 1;
        int c0 = ch * 15;
        const float* wr = w_r + d * 150;
        const float* wp = w0 + (uu * 2 + ci) * 150;
        float s = 0.f;
        for (int c = c0; c < c0 + 15; ++c) s += wr[c] * wp[c];
        wtA[idx] = s;
    }
    if (t < 90) {
        int d = t / 10, ch = t - d * 10, c0 = ch * 15;
        float s = 0.f;
        for (int c = c0; c < c0 + 15; ++c) s += w_r[d * 150 + c] * b0[c];
        Bt[t] = s;
    }
    __syncthreads();
    // ---- round B: reduce P entries (162) and B (9) ----
    if (t < 162) {
        float s = 0.f;
        #pragma unroll
        for (int i = 0; i < 10; ++i) s += wtA[t * 10 + i];
        int d = t / 18, rem = t % 18;
        int uu = rem >> 1, ci = rem & 1;
        int dy = d / 3 - 1, dx = d % 3 - 1;
        int uy = uu / 3 - 1, ux = uu % 3 - 1;
        int eidx = (dy + uy + 2) * 5 + (dx + ux + 2);
        Pp[d * 50 + eidx * 2 + ci] = s;
    } else if (t >= 256 && t < 265) {
        int d = t - 256;
        float s = 0.f;
        #pragma unroll
        for (int i = 0; i < 10; ++i) s += Bt[d * 10 + i];
        Bv[d] = s;
    }
    __syncthreads();
    // ---- round C: class subset-sums W5c[9][51] ----
    if (t < 459) {
        int cls = t / 51, j = t - cls * 51;
        int cy = cls / 3, cx = cls % 3;
        float s = 0.f;
        #pragma unroll
        for (int d = 0; d < 9; ++d) {
            int dy = d / 3 - 1, dx = d % 3 - 1;
            bool ok = (cy == 0 || (cy == 1 ? dy >= 0 : dy <= 0)) &&
                      (cx == 0 || (cx == 1 ? dx >= 0 : dx <= 0));
            if (ok) s += (j < 50) ? Pp[d * 50 + j] : Bv[d];
        }
        W5c[t] = s;
    }
    __syncthreads();

    // ---- r everywhere via class-weighted 5x5 stencil ----
    {
        int cy = (row == 0) ? 1 : (row == 63) ? 2 : 0;
        #pragma unroll
        for (int p = 0; p < 8; ++p) {
            int xx = cb + p;
            int cx = (xx == 0) ? 1 : (xx == 63) ? 2 : 0;
            const float* Wp = &W5c[(cy * 3 + cx) * 51];
            float acc = Wp[50];
            #pragma unroll
            for (int e = 0; e < 25; ++e) {
                int xi = (row + e / 5) * XROW + (xx + e % 5);
                acc = fmaf(xs0[xi], Wp[e * 2], acc);
                acc = fmaf(xs1[xi], Wp[e * 2 + 1], acc);
            }
            rs[(row + 1) * RROW + xx + 2] = acc;
        }
    }
    __syncthreads();

    const int K = VInum[0];

    // ---- Rsw precompute (packed action-pairs) + first step (w_q) ----
    v2f Rsw2[8][5];
    float vprev[8];
    {
        float rwin[3][10];
        #pragma unroll
        for (int i = 0; i < 3; ++i) {
            const float* rp = &rs[(row + i) * RROW + cb];
            float4 q0 = *(const float4*)(rp);
            float4 q1 = *(const float4*)(rp + 4);
            float4 q2 = *(const float4*)(rp + 8);
            rwin[i][0] = q0.y; rwin[i][1] = q0.z; rwin[i][2] = q0.w;
            rwin[i][3] = q1.x; rwin[i][4] = q1.y; rwin[i][5] = q1.z;
            rwin[i][6] = q1.w; rwin[i][7] = q2.x; rwin[i][8] = q2.y;
            rwin[i][9] = q2.z;
        }
        float vmax[8];
        #pragma unroll
        for (int a = 0; a < 10; ++a) {
            #pragma unroll
            for (int p = 0; p < 8; ++p) {
                float accR = 0.f, accQ = 0.f;
                #pragma unroll
                for (int d = 0; d < 9; ++d) {
                    float rv = rwin[d / 3][p + d % 3];
                    accR = fmaf(w_sw[d * 20 + a], rv, accR);
                    accQ = fmaf(w_q[d * 20 + a],  rv, accQ);
                }
                if (a & 1) Rsw2[p][a >> 1].y = accR; else Rsw2[p][a >> 1].x = accR;
                vmax[p] = (a == 0) ? accQ : fmaxf(vmax[p], accQ);
            }
        }
        #pragma unroll
        for (int p = 0; p < 8; ++p) {
            vpool[0 * VSTR2 + (row + 1) * VROW2 + cb + p + 2] = vmax[p];
            vprev[p] = vmax[p];
        }
    }
    __syncthreads();

    // ---- hoist loop-invariant weights into VGPRs (90 VGPR, once) ----
    v2f wreg[45];
    #pragma unroll
    for (int i = 0; i < 45; ++i) wreg[i] = swv2[i];

    // ---- K-1 shared-weight VI steps: pure VALU + in-order DS ----
    int cur = 0;
    for (int it = 0; it < K - 1; ++it) {
        const float* vbA = &vpool[cur * VSTR2 + row * VROW2 + cb];  // above row
        const float* vbM = vbA + VROW2;                              // center
        const float* vbB = vbA + 2 * VROW2;                          // below
        int nxt = cur ^ 1;

        // A-half loads (cols cb-1..cb+4 windows) + mid edges
        float4 aQ0 = *(const float4*)(vbA);
        float4 aQ1 = *(const float4*)(vbA + 4);
        float4 bQ0 = *(const float4*)(vbB);
        float4 bQ1 = *(const float4*)(vbB + 4);
        float eL = vbM[1];
        // B-half loads (issued early; covered by A compute)
        float4 aQ2 = *(const float4*)(vbA + 8);
        float4 bQ2 = *(const float4*)(vbB + 8);
        float eR = vbM[10];

        float av[10], bv[10], mid[10];
        av[0] = aQ0.y; av[1] = aQ0.z; av[2] = aQ0.w;
        av[3] = aQ1.x; av[4] = aQ1.y; av[5] = aQ1.z; av[6] = aQ1.w;
        av[7] = aQ2.x; av[8] = aQ2.y; av[9] = aQ2.z;
        bv[0] = bQ0.y; bv[1] = bQ0.z; bv[2] = bQ0.w;
        bv[3] = bQ1.x; bv[4] = bQ1.y; bv[5] = bQ1.z; bv[6] = bQ1.w;
        bv[7] = bQ2.x; bv[8] = bQ2.y; bv[9] = bQ2.z;
        mid[0] = eL; mid[9] = eR;
        #pragma unroll
        for (int j = 0; j < 8; ++j) mid[j + 1] = vprev[j];

        float vnew[8];
        // ---- half A: px 0..3 ----
        {
            v2f acc[4][5];
            #pragma unroll
            for (int ap = 0; ap < 5; ++ap)           // chunk: row above (d 0..2)
                #pragma unroll
                for (int dd = 0; dd < 3; ++dd) {
                    v2f w2 = wreg[dd * 5 + ap];
                    #pragma unroll
                    for (int p = 0; p < 4; ++p)
                        acc[p][ap] = (dd == 0) ? pkfma(w2, av[p + dd], Rsw2[p][ap])
                                               : pkfma(w2, av[p + dd], acc[p][ap]);
                }
            #pragma unroll
            for (int ap = 0; ap < 5; ++ap)           // chunk: center row (d 3..5)
                #pragma unroll
                for (int dd = 0; dd < 3; ++dd) {
                    v2f w2 = wreg[(3 + dd) * 5 + ap];
                    #pragma unroll
                    for (int p = 0; p < 4; ++p)
                        acc[p][ap] = pkfma(w2, mid[p + dd], acc[p][ap]);
                }
            #pragma unroll
            for (int ap = 0; ap < 5; ++ap)           // chunk: row below (d 6..8)
                #pragma unroll
                for (int dd = 0; dd < 3; ++dd) {
                    v2f w2 = wreg[(6 + dd) * 5 + ap];
                    #pragma unroll
                    for (int p = 0; p < 4; ++p)
                        acc[p][ap] = pkfma(w2, bv[p + dd], acc[p][ap]);
                }
            #pragma unroll
            for (int p = 0; p < 4; ++p) {
                v2f m2 = acc[p][0];
                #pragma unroll
                for (int ap = 1; ap < 5; ++ap) m2 = pkmax(m2, acc[p][ap]);
                vnew[p] = fmaxf(m2.x, m2.y);
            }
        }
        // ---- half B: px 4..7 ----
        {
            v2f acc[4][5];
            #pragma unroll
            for (int ap = 0; ap < 5; ++ap)
                #pragma unroll
                for (int dd = 0; dd < 3; ++dd) {
                    v2f w2 = wreg[dd * 5 + ap];
                    #pragma unroll
                    for (int p = 0; p < 4; ++p)
                        acc[p][ap] = (dd == 0) ? pkfma(w2, av[p + 4 + dd], Rsw2[p + 4][ap])
                                               : pkfma(w2, av[p + 4 + dd], acc[p][ap]);
                }
            #pragma unroll
            for (int ap = 0; ap < 5; ++ap)
                #pragma unroll
                for (int dd = 0; dd < 3; ++dd) {
                    v2f w2 = wreg[(3 + dd) * 5 + ap];
                    #pragma unroll
                    for (int p = 0; p < 4; ++p)
                        acc[p][ap] = pkfma(w2, mid[p + 4 + dd], acc[p][ap]);
                }
            #pragma unroll
            for (int ap = 0; ap < 5; ++ap)
                #pragma unroll
                for (int dd = 0; dd < 3; ++dd) {
                    v2f w2 = wreg[(6 + dd) * 5 + ap];
                    #pragma unroll
                    for (int p = 0; p < 4; ++p)
                        acc[p][ap] = pkfma(w2, bv[p + 4 + dd], acc[p][ap]);
                }
            #pragma unroll
            for (int p = 0; p < 4; ++p) {
                v2f m2 = acc[p][0];
                #pragma unroll
                for (int ap = 1; ap < 5; ++ap) m2 = pkmax(m2, acc[p][ap]);
                vnew[p + 4] = fmaxf(m2.x, m2.y);
            }
        }
        // ---- publish (4x ds_write_b64), carry ----
        float* vw = &vpool[nxt * VSTR2 + (row + 1) * VROW2 + cb + 2];
        *(float2*)&vw[0] = make_float2(vnew[0], vnew[1]);
        *(float2*)&vw[2] = make_float2(vnew[2], vnew[3]);
        *(float2*)&vw[4] = make_float2(vnew[4], vnew[5]);
        *(float2*)&vw[6] = make_float2(vnew[6], vnew[7]);
        #pragma unroll
        for (int p = 0; p < 8; ++p) vprev[p] = vnew[p];

        cur = nxt;
        __syncthreads();
    }

    // ---- final step with w_sw2: q -> global, gather (S1,S2) ----
    const int s1 = S1[b], s2 = S2[b];
    {
        float rwin[3][10], vwin[3][10];
        #pragma unroll
        for (int i = 0; i < 3; ++i) {
            const float* rp = &rs[(row + i) * RROW + cb];
            float4 q0 = *(const float4*)(rp);
            float4 q1 = *(const float4*)(rp + 4);
            float4 q2 = *(const float4*)(rp + 8);
            rwin[i][0] = q0.y; rwin[i][1] = q0.z; rwin[i][2] = q0.w;
            rwin[i][3] = q1.x; rwin[i][4] = q1.y; rwin[i][5] = q1.z;
            rwin[i][6] = q1.w; rwin[i][7] = q2.x; rwin[i][8] = q2.y;
            rwin[i][9] = q2.z;
        }
        {
            const float* vbA = &vpool[cur * VSTR2 + row * VROW2 + cb];
            const float* vbM = vbA + VROW2;
            const float* vbB = vbA + 2 * VROW2;
            float4 q0 = *(const float4*)(vbA);
            float4 q1 = *(const float4*)(vbA + 4);
            float4 q2 = *(const float4*)(vbA + 8);
            vwin[0][0] = q0.y; vwin[0][1] = q0.z; vwin[0][2] = q0.w;
            vwin[0][3] = q1.x; vwin[0][4] = q1.y; vwin[0][5] = q1.z;
            vwin[0][6] = q1.w; vwin[0][7] = q2.x; vwin[0][8] = q2.y;
            vwin[0][9] = q2.z;
            q0 = *(const float4*)(vbB);
            q1 = *(const float4*)(vbB + 4);
            q2 = *(const float4*)(vbB + 8);
            vwin[2][0] = q0.y; vwin[2][1] = q0.z; vwin[2][2] = q0.w;
            vwin[2][3] = q1.x; vwin[2][4] = q1.y; vwin[2][5] = q1.z;
            vwin[2][6] = q1.w; vwin[2][7] = q2.x; vwin[2][8] = q2.y;
            vwin[2][9] = q2.z;
            vwin[1][0] = vbM[1]; vwin[1][9] = vbM[10];
            #pragma unroll
            for (int j = 0; j < 8; ++j) vwin[1][j + 1] = vprev[j];
        }
        float qv[8][10];
        #pragma unroll
        for (int a = 0; a < 10; ++a) {
            #pragma unroll
            for (int p = 0; p < 8; ++p) {
                float acc = 0.f;
                #pragma unroll
                for (int d = 0; d < 9; ++d) {
                    acc = fmaf(w_sw2[d * 20 + a],      rwin[d / 3][p + d % 3], acc);
                    acc = fmaf(w_sw2[d * 20 + 10 + a], vwin[d / 3][p + d % 3], acc);
                }
                qv[p][a] = acc;
            }
        }
        // store q: 80 contiguous floats (8 px x 10 actions), 16B-aligned
        {
            float4* qp4 = (float4*)(out + 2048 + ((size_t)((b * 64 + row) * 64 + cb)) * 10);
            #pragma unroll
            for (int g = 0; g < 20; ++g)
                qp4[g] = make_float4(qv[(g * 4) / 10][(g * 4) % 10],
                                     qv[(g * 4 + 1) / 10][(g * 4 + 1) % 10],
                                     qv[(g * 4 + 2) / 10][(g * 4 + 2) % 10],
                                     qv[(g * 4 + 3) / 10][(g * 4 + 3) % 10]);
        }
        if (row == s1) {
            #pragma unroll
            for (int p = 0; p < 8; ++p)
                if (s2 == cb + p) {
                    #pragma unroll
                    for (int a = 0; a < 10; ++a) qsel[a] = qv[p][a];
                }
        }
    }
    __syncthreads();

    // ---- dense + softmax (thread 0), q_out (threads 0..9) ----
    if (t == 0) {
        float logits[8];
        float m = -1e30f;
        #pragma unroll
        for (int j = 0; j < 8; ++j) {
            float s = 0.f;
            #pragma unroll
            for (int a = 0; a < 10; ++a) s += qsel[a] * w_dense[a * 8 + j];
            logits[j] = s;
            m = fmaxf(m, s);
        }
        float sum = 0.f;
        float e[8];
        #pragma unroll
        for (int j = 0; j < 8; ++j) { e[j] = expf(logits[j] - m); sum += e[j]; }
        float inv = 1.f / sum;
        #pragma unroll
        for (int j = 0; j < 8; ++j) {
            out[b * 8 + j] = logits[j];
            out[1024 + b * 8 + j] = e[j] * inv;
        }
    }
    if (t < 10) out[5244928 + b * 10 + t] = qsel[t];
}

extern "C" void kernel_launch(void* const* d_in, const int* in_sizes, int n_in,
                              void* d_out, int out_size, void* d_ws, size_t ws_size,
                              hipStream_t stream) {
    const float* x      = (const float*)d_in[0];
    const int*   S1     = (const int*)d_in[1];
    const int*   S2     = (const int*)d_in[2];
    const int*   VInum  = (const int*)d_in[3];
    const float* w0     = (const float*)d_in[4];
    const float* b0     = (const float*)d_in[5];
    const float* w_r    = (const float*)d_in[6];
    const float* w_q    = (const float*)d_in[7];
    const float* w_sw   = (const float*)d_in[8];
    const float* w_sw2  = (const float*)d_in[9];
    const float* w_dense= (const float*)d_in[10];
    float* out = (float*)d_out;

    vin_kernel<<<128, 512, 0, stream>>>(x, S1, S2, VInum, w0, b0, w_r, w_q,
                                        w_sw, w_sw2, w_dense, out);
}

// Round 9
// 171.445 us; speedup vs baseline: 1.0651x; 1.0651x over previous
//
#include <hip/hip_runtime.h>
#include <math.h>

// VIN forward on MI355X — single fused kernel, 128 WGs x 1024 thr (16 waves).
// Sizes: N=128, H=W=64, CH_I=2, CH_H=150, CH_Q=10, N_ACT=8, VInum=36.
//
// R19 resubmit (R8 bench = container infra failure, no kernel verdict).
// R18 -> R19 (K-loop data movement, base = R17 which benched 104us):
//  R18 failed: allocator caps at 128 VGPR even at waves_per_eu(2,2) -> wreg
//  never register-resident; clustered b128 at 2 waves/SIMD regressed (R9/R17
//  lesson). New structure: the stencil's LDS window reads are 90% redundant
//  across lanes — replace with cross-lane DPP. Lane c owns COLUMN c, wave w
//  owns rows 4w..4w+3 (4 vertical px in registers). Horizontal neighbors:
//  v_mov_dpp wave_shr:1/wave_shl:1 (bound_ctrl -> 0 at lanes 0/63 = zero
//  halo), 12 VALU movs/iter. Vertical: rows r..r+3 = own vprev[4] regs;
//  only rows 4w-1/4w+4 cross waves -> parity-double-buffered exT/exB LDS
//  exchange (slot 16 always zero = image halo): 2 b32 reads + 2 b32 writes
//  per thread per iter (was ~8 wide ops); 36KB vpool deleted. Weights stay
//  on R17's s_load path. Same d=0..8 chain order, identical operand floats
//  -> bit-identical output.

typedef float v2f __attribute__((ext_vector_type(2)));

static __device__ __forceinline__ v2f splat2(float s) { v2f r; r.x = s; r.y = s; return r; }
static __device__ __forceinline__ v2f pkfma(v2f w, float v, v2f a) {
#if __has_builtin(__builtin_elementwise_fma)
    return __builtin_elementwise_fma(w, splat2(v), a);
#else
    v2f r; r.x = fmaf(w.x, v, a.x); r.y = fmaf(w.y, v, a.y); return r;
#endif
}
static __device__ __forceinline__ v2f pkmax(v2f a, v2f b) {
#if __has_builtin(__builtin_elementwise_max)
    return __builtin_elementwise_max(a, b);
#else
    v2f r; r.x = fmaxf(a.x, b.x); r.y = fmaxf(a.y, b.y); return r;
#endif
}

// DPP wave-wide shift by one lane. bound-invalid lanes keep old (=0) ->
// zero halo at lanes 0/63.
#define DPP_SHR1 0x138   // lane n <- lane n-1  (left-neighbor value)
#define DPP_SHL1 0x130   // lane n <- lane n+1  (right-neighbor value)
template <int CTRL>
static __device__ __forceinline__ float dppsh(float v) {
    return __int_as_float(__builtin_amdgcn_update_dpp(
        0, __float_as_int(v), CTRL, 0xF, 0xF, false));
}

#define XROW 69
#define RROW 68                  // rs row stride; idx = (grow+1)*68 + col + 2

__global__ void
__attribute__((amdgpu_flat_work_group_size(1024, 1024)))
__attribute__((amdgpu_waves_per_eu(4, 4)))
vin_kernel(const float* __restrict__ x,
           const int* __restrict__ S1,
           const int* __restrict__ S2,
           const int* __restrict__ VInum,
           const float* __restrict__ w0,
           const float* __restrict__ b0,
           const float* __restrict__ w_r,
           const float* __restrict__ w_q,
           const float* __restrict__ w_sw,
           const float* __restrict__ w_sw2,
           const float* __restrict__ w_dense,
           float* __restrict__ out) {
    const int b = blockIdx.x;
    const int t = threadIdx.x;

    __shared__ float xs0[68 * XROW];     // x ch0, [y+2][x+2], 2-halo of zeros
    __shared__ float xs1[68 * XROW];     // x ch1
    __shared__ float rs[66 * RROW];      // r, pad-2 layout, zero halos
    __shared__ float wtA[1620];          // P chunk partials: 162 entries x 10
    __shared__ float Pp[450];            // P[d][e5x5][ci], zero-init
    __shared__ float Bt[90];             // bias chunk partials
    __shared__ float Bv[9];              // B[d] = w_r[d].b0
    __shared__ float W5c[459];           // 9 classes x (50 weights + bias)
    __shared__ float exT[2][17][64];     // per-wave TOP-row edge, by parity
    __shared__ float exB[2][17][64];     // per-wave BOTTOM-row edge, by parity
    __shared__ float qsel[10];

    // ---- zero LDS (halos/slot-16 must be 0; Pp must be 0) ----
    for (int i = t; i < 68 * XROW; i += 1024) { xs0[i] = 0.f; xs1[i] = 0.f; }
    for (int i = t; i < 66 * RROW; i += 1024) rs[i] = 0.f;
    for (int i = t; i < 2 * 17 * 64; i += 1024) {
        ((float*)exT)[i] = 0.f; ((float*)exB)[i] = 0.f;
    }
    if (t < 450) Pp[t] = 0.f;
    __syncthreads();

    const int row = t >> 4;          // 0..63 (prologue mapping)
    const int cb  = (t & 15) << 2;   // 0,4,...,60

    // ---- stage x (8 contiguous floats = 2x float4 per thread) ----
    {
        const float* xb = x + (size_t)b * 64 * 64 * 2;
        const float4* xp = (const float4*)(xb + (row * 64 + cb) * 2);
        #pragma unroll
        for (int g = 0; g < 2; ++g) {
            float4 v4 = xp[g];
            int px = cb + g * 2;
            xs0[(row + 2) * XROW + px + 2] = v4.x;
            xs1[(row + 2) * XROW + px + 2] = v4.y;
            xs0[(row + 2) * XROW + px + 3] = v4.z;
            xs1[(row + 2) * XROW + px + 3] = v4.w;
        }
    }
    // ---- round A: P chunk partials (1620 items) + bias chunks (90) ----
    for (int idx = t; idx < 1620; idx += 1024) {
        int entry = idx / 10, ch = idx - entry * 10;
        int d = entry / 18, rem = entry % 18;
        int uu = rem >> 1, ci = rem & 1;
        int c0 = ch * 15;
        const float* wr = w_r + d * 150;
        const float* wp = w0 + (uu * 2 + ci) * 150;
        float s = 0.f;
        for (int c = c0; c < c0 + 15; ++c) s += wr[c] * wp[c];
        wtA[idx] = s;
    }
    if (t < 90) {
        int d = t / 10, ch = t - d * 10, c0 = ch * 15;
        float s = 0.f;
        for (int c = c0; c < c0 + 15; ++c) s += w_r[d * 150 + c] * b0[c];
        Bt[t] = s;
    }
    __syncthreads();
    // ---- round B: reduce P entries (162) and B (9) ----
    if (t < 162) {
        float s = 0.f;
        #pragma unroll
        for (int i = 0; i < 10; ++i) s += wtA[t * 10 + i];
        int d = t / 18, rem = t % 18;
        int uu = rem >> 1, ci = rem & 1;
        int dy = d / 3 - 1, dx = d % 3 - 1;
        int uy = uu / 3 - 1, ux = uu % 3 - 1;
        int eidx = (dy + uy + 2) * 5 + (dx + ux + 2);
        Pp[d * 50 + eidx * 2 + ci] = s;
    } else if (t >= 256 && t < 265) {
        int d = t - 256;
        float s = 0.f;
        #pragma unroll
        for (int i = 0; i < 10; ++i) s += Bt[d * 10 + i];
        Bv[d] = s;
    }
    __syncthreads();
    // ---- round C: class subset-sums W5c[9][51] ----
    if (t < 459) {
        int cls = t / 51, j = t - cls * 51;
        int cy = cls / 3, cx = cls % 3;
        float s = 0.f;
        #pragma unroll
        for (int d = 0; d < 9; ++d) {
            int dy = d / 3 - 1, dx = d % 3 - 1;
            bool ok = (cy == 0 || (cy == 1 ? dy >= 0 : dy <= 0)) &&
                      (cx == 0 || (cx == 1 ? dx >= 0 : dx <= 0));
            if (ok) s += (j < 50) ? Pp[d * 50 + j] : Bv[d];
        }
        W5c[t] = s;
    }
    __syncthreads();

    // ---- r everywhere via class-weighted 5x5 stencil (4 px/thread) ----
    {
        int cy = (row == 0) ? 1 : (row == 63) ? 2 : 0;
        #pragma unroll
        for (int p = 0; p < 4; ++p) {
            int xx = cb + p;
            int cx = (xx == 0) ? 1 : (xx == 63) ? 2 : 0;
            const float* Wp = &W5c[(cy * 3 + cx) * 51];
            float acc = Wp[50];
            #pragma unroll
            for (int e = 0; e < 25; ++e) {
                int xi = (row + e / 5) * XROW + (xx + e % 5);
                acc = fmaf(xs0[xi], Wp[e * 2], acc);
                acc = fmaf(xs1[xi], Wp[e * 2 + 1], acc);
            }
            rs[(row + 1) * RROW + xx + 2] = acc;
        }
    }
    __syncthreads();

    // ============ column-per-lane mapping from here on ============
    const int c  = t & 63;           // column 0..63 (lane)
    const int w  = t >> 6;           // wave 0..15, owns rows 4w..4w+3
    const int r0 = w << 2;
    const int upSlot = (w == 0)  ? 16 : w - 1;   // exB[.][upSlot] = row r0-1
    const int dnSlot = (w == 15) ? 16 : w + 1;   // exT[.][dnSlot] = row r0+4
    const int K = VInum[0];

    // ---- Rsw precompute + first step (w_q): r window via DPP ----
    v2f Rsw2[4][5];
    float vprev[4];
    float RC[6], RL[6], RR[6];
    #pragma unroll
    for (int j = 0; j < 6; ++j) RC[j] = rs[(r0 + j) * RROW + c + 2];  // rows r0-1..r0+4
    #pragma unroll
    for (int j = 0; j < 6; ++j) { RL[j] = dppsh<DPP_SHR1>(RC[j]); RR[j] = dppsh<DPP_SHL1>(RC[j]); }
    {
        float vmax[4];
        #pragma unroll
        for (int a = 0; a < 10; ++a) {
            #pragma unroll
            for (int i = 0; i < 4; ++i) {
                float accR = 0.f, accQ = 0.f;
                #pragma unroll
                for (int d = 0; d < 9; ++d) {
                    const int dy = d / 3, dx = d % 3;
                    const float rv = (dx == 0 ? RL : dx == 1 ? RC : RR)[i + dy];
                    accR = fmaf(w_sw[d * 20 + a], rv, accR);
                    accQ = fmaf(w_q[d * 20 + a],  rv, accQ);
                }
                if (a & 1) Rsw2[i][a >> 1].y = accR; else Rsw2[i][a >> 1].x = accR;
                vmax[i] = (a == 0) ? accQ : fmaxf(vmax[i], accQ);
            }
        }
        exT[1][w][c] = vmax[0];          // v^1 edges, parity 1
        exB[1][w][c] = vmax[3];
        #pragma unroll
        for (int i = 0; i < 4; ++i) vprev[i] = vmax[i];
    }
    __syncthreads();

    // ---- K-1 shared-weight VI steps: register v + DPP + edge exchange ----
    const float* wsv = w_sw + 10;        // v-part weights (uniform s_loads)
    for (int k = 2; k <= K; ++k) {
        const int pr = (k - 1) & 1, pw = k & 1;
        float VC[6], VL[6], VR[6];
        VC[0] = exB[pr][upSlot][c];      // row r0-1 (neighbor wave / halo 0)
        VC[5] = exT[pr][dnSlot][c];      // row r0+4
        #pragma unroll
        for (int i = 0; i < 4; ++i) VC[i + 1] = vprev[i];
        #pragma unroll
        for (int j = 0; j < 6; ++j) { VL[j] = dppsh<DPP_SHR1>(VC[j]); VR[j] = dppsh<DPP_SHL1>(VC[j]); }

        v2f acc[4][5];
        #pragma unroll
        for (int ap = 0; ap < 5; ++ap) {
            #pragma unroll
            for (int d = 0; d < 9; ++d) {
                v2f w2; w2.x = wsv[d * 20 + 2 * ap]; w2.y = wsv[d * 20 + 2 * ap + 1];
                const int dy = d / 3, dx = d % 3;
                const float* S = (dx == 0) ? VL : (dx == 1) ? VC : VR;
                #pragma unroll
                for (int i = 0; i < 4; ++i)
                    acc[i][ap] = (d == 0) ? pkfma(w2, S[i + dy], Rsw2[i][ap])
                                          : pkfma(w2, S[i + dy], acc[i][ap]);
            }
        }
        float vnew[4];
        #pragma unroll
        for (int i = 0; i < 4; ++i) {
            v2f m2 = acc[i][0];
            #pragma unroll
            for (int ap = 1; ap < 5; ++ap) m2 = pkmax(m2, acc[i][ap]);
            vnew[i] = fmaxf(m2.x, m2.y);
        }
        exT[pw][w][c] = vnew[0];         // publish v^k edges
        exB[pw][w][c] = vnew[3];
        #pragma unroll
        for (int i = 0; i < 4; ++i) vprev[i] = vnew[i];
        __syncthreads();
    }

    // ---- final step with w_sw2: q -> global, gather (S1,S2) ----
    const int s1 = S1[b], s2 = S2[b];
    {
        const int pK = K & 1;
        float VC[6], VL[6], VR[6];
        VC[0] = exB[pK][upSlot][c];
        VC[5] = exT[pK][dnSlot][c];
        #pragma unroll
        for (int i = 0; i < 4; ++i) VC[i + 1] = vprev[i];
        #pragma unroll
        for (int j = 0; j < 6; ++j) { VL[j] = dppsh<DPP_SHR1>(VC[j]); VR[j] = dppsh<DPP_SHL1>(VC[j]); }

        float qv[4][10];
        #pragma unroll
        for (int a = 0; a < 10; ++a) {
            #pragma unroll
            for (int i = 0; i < 4; ++i) {
                float acc = 0.f;
                #pragma unroll
                for (int d = 0; d < 9; ++d) {
                    const int dy = d / 3, dx = d % 3;
                    acc = fmaf(w_sw2[d * 20 + a],
                               (dx == 0 ? RL : dx == 1 ? RC : RR)[i + dy], acc);
                    acc = fmaf(w_sw2[d * 20 + 10 + a],
                               (dx == 0 ? VL : dx == 1 ? VC : VR)[i + dy], acc);
                }
                qv[i][a] = acc;
            }
        }
        // store q: 10 floats per px, 8B-aligned -> 5x float2 per row
        #pragma unroll
        for (int i = 0; i < 4; ++i) {
            float2* qp = (float2*)(out + 2048 +
                          ((size_t)((b * 64 + r0 + i) * 64 + c)) * 10);
            #pragma unroll
            for (int g = 0; g < 5; ++g)
                qp[g] = make_float2(qv[i][2 * g], qv[i][2 * g + 1]);
        }
        if (c == s2) {
            #pragma unroll
            for (int i = 0; i < 4; ++i)
                if (s1 == r0 + i) {
                    #pragma unroll
                    for (int a = 0; a < 10; ++a) qsel[a] = qv[i][a];
                }
        }
    }
    __syncthreads();

    // ---- dense + softmax (thread 0), q_out (threads 0..9) ----
    if (t == 0) {
        float logits[8];
        float m = -1e30f;
        #pragma unroll
        for (int j = 0; j < 8; ++j) {
            float s = 0.f;
            #pragma unroll
            for (int a = 0; a < 10; ++a) s += qsel[a] * w_dense[a * 8 + j];
            logits[j] = s;
            m = fmaxf(m, s);
        }
        float sum = 0.f;
        float e[8];
        #pragma unroll
        for (int j = 0; j < 8; ++j) { e[j] = expf(logits[j] - m); sum += e[j]; }
        float inv = 1.f / sum;
        #pragma unroll
        for (int j = 0; j < 8; ++j) {
            out[b * 8 + j] = logits[j];
            out[1024 + b * 8 + j] = e[j] * inv;
        }
    }
    if (t < 10) out[5244928 + b * 10 + t] = qsel[t];
}

extern "C" void kernel_launch(void* const* d_in, const int* in_sizes, int n_in,
                              void* d_out, int out_size, void* d_ws, size_t ws_size,
                              hipStream_t stream) {
    const float* x      = (const float*)d_in[0];
    const int*   S1     = (const int*)d_in[1];
    const int*   S2     = (const int*)d_in[2];
    const int*   VInum  = (const int*)d_in[3];
    const float* w0     = (const float*)d_in[4];
    const float* b0     = (const float*)d_in[5];
    const float* w_r    = (const float*)d_in[6];
    const float* w_q    = (const float*)d_in[7];
    const float* w_sw   = (const float*)d_in[8];
    const float* w_sw2  = (const float*)d_in[9];
    const float* w_dense= (const float*)d_in[10];
    float* out = (float*)d_out;

    vin_kernel<<<128, 1024, 0, stream>>>(x, S1, S2, VInum, w0, b0, w_r, w_q,
                                         w_sw, w_sw2, w_dense, out);
}